// Round 2
// baseline (87047.119 us; speedup 1.0000x reference)
//
#include <hip/hip_runtime.h>
#include <cstdint>
#include <cstddef>

// Problem constants
#define BB 64
#define TT 1024
#define HH 512
#define EE 128
#define SS 128
#define II 32

// ws offsets (in floats)
#define OFF_LOGITS 0          // 65536
#define OFF_CTX    65536      // 32768
#define OFF_POOL   98304      // 32768
#define OFF_PRECTX 131072     // 131072  (B x 4H)
#define OFF_WH     262144     // 1048576 (4H x H)
#define OFF_EMBW   1310720    // 129*2048 = 264192
#define OFF_HBUF   1574912    // 32768
#define OFF_CBUF   1607680    // 32768
#define OFF_SEL    1640448    // 64 uints
#define OFF_CTR    1640512    // 512 uints (8 groups x 64 padding)
#define OFF_PRE    2097152    // chunked pre_enc: Tc*64*2048

// ---------------------------------------------------------------- init
__global__ void k_init(float* out, const float* lstm_h, const float* lstm_c, float* ws) {
  size_t gid = (size_t)blockIdx.x * 256 + threadIdx.x;
  float4* o4 = (float4*)out;
  const float4 z = make_float4(0.f, 0.f, 0.f, 0.f);
  for (size_t i = gid; i < 2097152u; i += (size_t)gridDim.x * 256) o4[i] = z; // zero slot_logp
  if (gid < 8192) {
    ((float4*)(ws + OFF_HBUF))[gid] = ((const float4*)lstm_h)[gid];
    ((float4*)(ws + OFF_CBUF))[gid] = ((const float4*)lstm_c)[gid];
  }
  if (gid < 64)  ((unsigned*)(ws + OFF_SEL))[gid] = 128u;  // init_slot row
  if (gid < 512) ((unsigned*)(ws + OFF_CTR))[gid] = 0u;
}

// ------------------------------------------------------- attention logits
__global__ void k_att_logits(const float* __restrict__ enc, const float* __restrict__ att_w,
                             const float* __restrict__ att_b, float* __restrict__ logits) {
  int row = blockIdx.x * 4 + (threadIdx.x >> 6);  // row = b*1024 + t
  int lane = threadIdx.x & 63;
  const float* er = enc + (size_t)row * HH;
  const float* w2 = att_w + HH;
  float acc = 0.f;
  #pragma unroll
  for (int j = 0; j < 8; ++j) acc = fmaf(er[lane + j * 64], w2[lane + j * 64], acc);
  #pragma unroll
  for (int d = 1; d < 64; d <<= 1) acc += __shfl_xor(acc, d, 64);
  if (lane == 0) logits[row] = acc + att_b[0];
}

// --------------------------------------- softmax + context + pooled (per b)
__global__ void k_att_ctx(const float* __restrict__ enc, const float* __restrict__ logits,
                          const int* __restrict__ lens, float* __restrict__ ctx,
                          float* __restrict__ pool) {
  int b = blockIdx.x, tid = threadIdx.x;
  int len = lens[b];
  __shared__ float ew[TT];
  __shared__ float red[8];
  float m = -3.0e38f;
  for (int t = tid; t < TT; t += 256) m = fmaxf(m, (t < len) ? logits[b * TT + t] : -3.0e38f);
  #pragma unroll
  for (int d = 1; d < 64; d <<= 1) m = fmaxf(m, __shfl_xor(m, d, 64));
  if ((tid & 63) == 0) red[tid >> 6] = m;
  __syncthreads();
  m = fmaxf(fmaxf(red[0], red[1]), fmaxf(red[2], red[3]));
  __syncthreads();
  float s = 0.f;
  for (int t = tid; t < TT; t += 256) {
    float e = (t < len) ? expf(logits[b * TT + t] - m) : 0.f;
    ew[t] = e; s += e;
  }
  #pragma unroll
  for (int d = 1; d < 64; d <<= 1) s += __shfl_xor(s, d, 64);
  if ((tid & 63) == 0) red[tid >> 6] = s;
  __syncthreads();
  s = red[0] + red[1] + red[2] + red[3];
  float inv = 1.f / s;
  float invlen = 1.f / (float)len;
  float c0 = 0.f, c1 = 0.f, p0 = 0.f, p1 = 0.f;
  const float* eb = enc + (size_t)b * TT * HH;
  for (int t = 0; t < TT; ++t) {
    float e = ew[t];
    float x0 = eb[t * HH + tid];
    float x1 = eb[t * HH + tid + 256];
    c0 = fmaf(e, x0, c0); c1 = fmaf(e, x1, c1);
    if (t < len) { p0 += x0; p1 += x1; }
  }
  ctx[b * HH + tid] = c0 * inv;
  ctx[b * HH + tid + 256] = c1 * inv;
  pool[b * HH + tid] = p0 * invlen;
  pool[b * HH + tid + 256] = p1 * invlen;
}

// ----------------------------------------------------------------- intent
__global__ void k_intent(const float* __restrict__ ctx, const float* __restrict__ pool,
                         const float* __restrict__ W_int, const float* __restrict__ b_int,
                         float* __restrict__ out_int) {
  int b = blockIdx.x, tid = threadIdx.x;  // 128 threads
  __shared__ float x[1024];
  __shared__ float lg[II];
  __shared__ float lz;
  for (int i = tid; i < HH; i += 128) { x[i] = ctx[b * HH + i]; x[HH + i] = pool[b * HH + i]; }
  __syncthreads();
  int s = tid >> 2, q = tid & 3;
  const float* wr = W_int + (size_t)s * 1024 + q * 256;
  const float* xr = x + q * 256;
  float acc = 0.f;
  #pragma unroll 4
  for (int k = 0; k < 256; ++k) acc = fmaf(wr[k], xr[k], acc);
  acc += __shfl_xor(acc, 1, 64);
  acc += __shfl_xor(acc, 2, 64);
  if (q == 0) lg[s] = acc + b_int[s];
  __syncthreads();
  if (tid == 0) {
    float M = lg[0];
    for (int i = 1; i < II; ++i) M = fmaxf(M, lg[i]);
    float S = 0.f;
    for (int i = 0; i < II; ++i) S += expf(lg[i] - M);
    lz = M + logf(S);
  }
  __syncthreads();
  if (tid < II) out_int[b * II + tid] = lg[tid] - lz;
}

// ------------------------------------------------- Wh = W_ih[:, :H] + W_hh
__global__ void k_wh(const float* __restrict__ W_ih, const float* __restrict__ W_hh,
                     float* __restrict__ Wh) {
  int i = blockIdx.x * 256 + threadIdx.x;  // float4 index, 262144 total
  int r = i >> 7, kq = i & 127;
  float4 a = ((const float4*)W_ih)[(size_t)r * 416 + kq];  // 1664/4 = 416
  float4 c = ((const float4*)W_hh)[i];
  ((float4*)Wh)[i] = make_float4(a.x + c.x, a.y + c.y, a.z + c.z, a.w + c.w);
}

// -------------------------------- embW[s][r] = emb_s . W_ih[r, 512:640]
__global__ void k_embw(const float* __restrict__ W_ih, const float* __restrict__ table,
                       const float* __restrict__ init_slot, float* __restrict__ embW) {
  int idx = blockIdx.x * 256 + threadIdx.x;  // 129*2048 = 264192 exact
  int s = idx >> 11, rr = idx & 2047;
  const float* tr = (s < SS) ? (table + (size_t)s * EE) : init_slot;
  const float* wr = W_ih + (size_t)rr * 1664 + 512;
  float a0 = 0.f, a1 = 0.f, a2 = 0.f, a3 = 0.f;
  #pragma unroll 4
  for (int e = 0; e < EE; e += 4) {
    a0 = fmaf(tr[e + 0], wr[e + 0], a0);
    a1 = fmaf(tr[e + 1], wr[e + 1], a1);
    a2 = fmaf(tr[e + 2], wr[e + 2], a2);
    a3 = fmaf(tr[e + 3], wr[e + 3], a3);
  }
  embW[idx] = (a0 + a1) + (a2 + a3);
}

// ------------- pre_ctx[b][r] = ctx[b] . W_ih[r,1152:1664] + b_ih[r]+b_hh[r]
__global__ void k_prectx(const float* __restrict__ W_ih, const float* __restrict__ ctx,
                         const float* __restrict__ b_ih, const float* __restrict__ b_hh,
                         float* __restrict__ pre) {
  int idx = blockIdx.x * 256 + threadIdx.x;  // 131072
  int b = idx >> 11, rr = idx & 2047;
  const float* cr = ctx + (size_t)b * HH;
  const float* wr = W_ih + (size_t)rr * 1664 + 1152;
  float a0 = 0.f, a1 = 0.f, a2 = 0.f, a3 = 0.f;
  #pragma unroll 4
  for (int k = 0; k < HH; k += 4) {
    a0 = fmaf(cr[k + 0], wr[k + 0], a0);
    a1 = fmaf(cr[k + 1], wr[k + 1], a1);
    a2 = fmaf(cr[k + 2], wr[k + 2], a2);
    a3 = fmaf(cr[k + 3], wr[k + 3], a3);
  }
  pre[idx] = (a0 + a1) + (a2 + a3) + b_ih[rr] + b_hh[rr];
}

// ---------------- pre_enc chunk GEMM: out[(tl*64+b)][r] = enc[b,t,:] . W_enc[r,:]
__global__ __launch_bounds__(256, 2) void k_pre_enc(const float* __restrict__ enc,
                                                    const float* __restrict__ W_ih,
                                                    float* __restrict__ pre, int ct0) {
  const int tl = blockIdx.x;
  const int r0 = blockIdx.y * 64;
  const int tg = ct0 + tl;
  const int tid = threadIdx.x;
  __shared__ float As[16][68];
  __shared__ float Bs[16][68];
  float acc[4][4] = {{0.f}};
  const int i4 = tid >> 4, j4 = tid & 15;
  const int lr = tid >> 2;
  const int lk = (tid & 3) * 4;
  const float* encb = enc + (size_t)lr * (TT * HH) + (size_t)tg * HH;  // row b = lr
  const float* wb = W_ih + (size_t)(r0 + lr) * 1664 + 640;
  for (int ks = 0; ks < HH; ks += 16) {
    float4 av = *(const float4*)(encb + ks + lk);
    float4 bv = *(const float4*)(wb + ks + lk);
    __syncthreads();
    As[lk + 0][lr] = av.x; As[lk + 1][lr] = av.y; As[lk + 2][lr] = av.z; As[lk + 3][lr] = av.w;
    Bs[lk + 0][lr] = bv.x; Bs[lk + 1][lr] = bv.y; Bs[lk + 2][lr] = bv.z; Bs[lk + 3][lr] = bv.w;
    __syncthreads();
    #pragma unroll
    for (int kk = 0; kk < 16; ++kk) {
      float4 a4 = *(const float4*)(&As[kk][i4 * 4]);
      float4 b4 = *(const float4*)(&Bs[kk][j4 * 4]);
      acc[0][0] = fmaf(a4.x, b4.x, acc[0][0]); acc[0][1] = fmaf(a4.x, b4.y, acc[0][1]);
      acc[0][2] = fmaf(a4.x, b4.z, acc[0][2]); acc[0][3] = fmaf(a4.x, b4.w, acc[0][3]);
      acc[1][0] = fmaf(a4.y, b4.x, acc[1][0]); acc[1][1] = fmaf(a4.y, b4.y, acc[1][1]);
      acc[1][2] = fmaf(a4.y, b4.z, acc[1][2]); acc[1][3] = fmaf(a4.y, b4.w, acc[1][3]);
      acc[2][0] = fmaf(a4.z, b4.x, acc[2][0]); acc[2][1] = fmaf(a4.z, b4.y, acc[2][1]);
      acc[2][2] = fmaf(a4.z, b4.z, acc[2][2]); acc[2][3] = fmaf(a4.z, b4.w, acc[2][3]);
      acc[3][0] = fmaf(a4.w, b4.x, acc[3][0]); acc[3][1] = fmaf(a4.w, b4.y, acc[3][1]);
      acc[3][2] = fmaf(a4.w, b4.z, acc[3][2]); acc[3][3] = fmaf(a4.w, b4.w, acc[3][3]);
    }
  }
  float* po = pre + ((size_t)tl * 64 + i4 * 4) * 2048 + r0 + j4 * 4;
  #pragma unroll
  for (int ii = 0; ii < 4; ++ii)
    *((float4*)(po + (size_t)ii * 2048)) = make_float4(acc[ii][0], acc[ii][1], acc[ii][2], acc[ii][3]);
}

// ---------------------------------------------------------------- scan
// 8 groups of 32 blocks; group g = blocks with blockIdx&7==g (same XCD under
// round-robin dispatch -> barrier + h/sel traffic stays XCD-local in L2).
__device__ __forceinline__ void group_barrier(unsigned* c, unsigned target) {
  __syncthreads();
  if (threadIdx.x == 0) {
    unsigned old = __hip_atomic_fetch_add(c, 1u, __ATOMIC_ACQ_REL, __HIP_MEMORY_SCOPE_AGENT);
    if (old + 1u < target) {
      int polls = 0;
      while (__hip_atomic_load(c, __ATOMIC_ACQUIRE, __HIP_MEMORY_SCOPE_AGENT) < target) {
        if (++polls > 32) __builtin_amdgcn_s_sleep(1);  // fast path first, then back off
      }
    }
  }
  __syncthreads();
}

__global__ __launch_bounds__(512, 1) void k_scan(float* ws, const int* __restrict__ seq_lens,
                                                 const float* __restrict__ W_slot,
                                                 const float* __restrict__ b_slot,
                                                 float* __restrict__ out_slot,
                                                 int t0, int t1, int ct0) {
  float* hbuf = ws + OFF_HBUF;
  float* cbuf = ws + OFF_CBUF;
  unsigned* sel = (unsigned*)(ws + OFF_SEL);
  unsigned* ctr = (unsigned*)(ws + OFF_CTR);
  const float* Wh = ws + OFF_WH;
  const float* embW = ws + OFF_EMBW;
  const float* prectx = ws + OFF_PRECTX;
  const float* pre = ws + OFF_PRE;

  const int gid = blockIdx.x;
  const int grp = gid & 7;        // 8 groups (XCD-aligned under round-robin)
  const int bk = gid >> 3;        // 32 blocks per group
  const int b0 = grp * 8;
  const int tid = threadIdx.x;
  const int bi = tid >> 6;        // local b (one wave per b)
  const int b = b0 + bi;
  const int lane = tid & 63;
  const int p = lane >> 2;        // h-position within block slice
  const int g = lane & 3;         // gate index i,f,g,o
  const int pglob = bk * 16 + p;  // 0..511
  const int r = g * 512 + pglob;  // gate row 0..2047
  unsigned* myctr = ctr + grp * 64;  // padded counters, no false sharing

  __shared__ float hs[8][512];
  __shared__ float hslot[512];
  __shared__ float slog[128];
  __shared__ float swred[8];
  __shared__ float swav[8];
  __shared__ int swai[8];
  __shared__ int lenS[8];

  if (tid < 8) lenS[tid] = seq_lens[b0 + tid];
  __syncthreads();
  int gmax = 0;
  #pragma unroll
  for (int i = 0; i < 8; ++i) gmax = max(gmax, lenS[i]);
  const int tmax = min(t1, gmax);
  const int len_b = lenS[bi];

  float cr = cbuf[(size_t)b * 512 + pglob];  // live c (used by g==0 lanes)

  {
    const float4* h4 = (const float4*)(hbuf + (size_t)b0 * 512);
    float4* hs4 = (float4*)(&hs[0][0]);
    for (int i = tid; i < 1024; i += 512) hs4[i] = h4[i];
  }
  __syncthreads();

  for (int t = t0; t < tmax; ++t) {
    const bool active = (t < len_b);  // wave-uniform
    float gate = 0.f;
    if (active) {
      const unsigned sb = sel[b];
      float pr = pre[((size_t)(t - ct0) * 64 + b) * 2048 + r]
               + prectx[(size_t)b * 2048 + r]
               + embW[(size_t)sb * 2048 + r];
      const float4* wrow = (const float4*)(Wh + (size_t)r * 512);
      const float4* hrow = (const float4*)(&hs[bi][0]);
      float a0 = 0.f, a1 = 0.f, a2 = 0.f, a3 = 0.f;  // 4 chains: hide 4-cyc fma latency
      #pragma unroll 2
      for (int k4 = 0; k4 < 128; k4 += 4) {
        float4 w0 = wrow[k4];     float4 h0 = hrow[k4];
        float4 w1 = wrow[k4 + 1]; float4 h1 = hrow[k4 + 1];
        float4 w2 = wrow[k4 + 2]; float4 h2 = hrow[k4 + 2];
        float4 w3 = wrow[k4 + 3]; float4 h3 = hrow[k4 + 3];
        a0 = fmaf(w0.x, h0.x, a0); a0 = fmaf(w0.y, h0.y, a0);
        a0 = fmaf(w0.z, h0.z, a0); a0 = fmaf(w0.w, h0.w, a0);
        a1 = fmaf(w1.x, h1.x, a1); a1 = fmaf(w1.y, h1.y, a1);
        a1 = fmaf(w1.z, h1.z, a1); a1 = fmaf(w1.w, h1.w, a1);
        a2 = fmaf(w2.x, h2.x, a2); a2 = fmaf(w2.y, h2.y, a2);
        a2 = fmaf(w2.z, h2.z, a2); a2 = fmaf(w2.w, h2.w, a2);
        a3 = fmaf(w3.x, h3.x, a3); a3 = fmaf(w3.y, h3.y, a3);
        a3 = fmaf(w3.z, h3.z, a3); a3 = fmaf(w3.w, h3.w, a3);
      }
      gate = (a0 + a1) + (a2 + a3) + pr;
    }
    const int base = lane & ~3;
    float gf = __shfl(gate, base + 1, 64);
    float gg = __shfl(gate, base + 2, 64);
    float go = __shfl(gate, base + 3, 64);
    if (active && g == 0) {
      float si = 1.f / (1.f + expf(-gate));
      float sf = 1.f / (1.f + expf(-gf));
      float so = 1.f / (1.f + expf(-go));
      float c_new = fmaf(sf, cr, si * tanhf(gg));
      float h_new = so * tanhf(c_new);
      cr = c_new;
      hbuf[(size_t)b * 512 + pglob] = h_new;
    }
    group_barrier(myctr, 32u * (2u * (unsigned)t + 1u));

    // ---- slot phase: blocks 0..7 of the group each own one b
    if (bk < 8) {
      const int bs = b0 + bk;
      if (t < lenS[bk]) {
        hslot[tid] = hbuf[(size_t)bs * 512 + tid];
        __syncthreads();
        const int s = tid >> 2, q = tid & 3;
        const float4* wr4 = (const float4*)(W_slot + (size_t)s * 512 + q * 128);
        const float4* hr4 = (const float4*)(hslot + q * 128);
        float a0 = 0.f, a1 = 0.f, a2 = 0.f, a3 = 0.f;
        #pragma unroll
        for (int k = 0; k < 32; k += 4) {
          float4 w0 = wr4[k];     float4 h0 = hr4[k];
          float4 w1 = wr4[k + 1]; float4 h1 = hr4[k + 1];
          float4 w2 = wr4[k + 2]; float4 h2 = hr4[k + 2];
          float4 w3 = wr4[k + 3]; float4 h3 = hr4[k + 3];
          a0 = fmaf(w0.x, h0.x, a0); a0 = fmaf(w0.y, h0.y, a0);
          a0 = fmaf(w0.z, h0.z, a0); a0 = fmaf(w0.w, h0.w, a0);
          a1 = fmaf(w1.x, h1.x, a1); a1 = fmaf(w1.y, h1.y, a1);
          a1 = fmaf(w1.z, h1.z, a1); a1 = fmaf(w1.w, h1.w, a1);
          a2 = fmaf(w2.x, h2.x, a2); a2 = fmaf(w2.y, h2.y, a2);
          a2 = fmaf(w2.z, h2.z, a2); a2 = fmaf(w2.w, h2.w, a2);
          a3 = fmaf(w3.x, h3.x, a3); a3 = fmaf(w3.y, h3.y, a3);
          a3 = fmaf(w3.z, h3.z, a3); a3 = fmaf(w3.w, h3.w, a3);
        }
        float acc = (a0 + a1) + (a2 + a3);
        acc += __shfl_xor(acc, 1, 64);
        acc += __shfl_xor(acc, 2, 64);
        acc += b_slot[s];
        if (q == 0) slog[s] = acc;
        __syncthreads();
        float v = (tid < 128) ? slog[tid] : -3.0e38f;
        float m = v;
        #pragma unroll
        for (int d = 1; d < 64; d <<= 1) m = fmaxf(m, __shfl_xor(m, d, 64));
        if (lane == 0) swred[tid >> 6] = m;
        __syncthreads();
        float M = swred[0];
        #pragma unroll
        for (int w = 1; w < 8; ++w) M = fmaxf(M, swred[w]);
        float e = (tid < 128) ? expf(v - M) : 0.f;
        float ssm = e;
        #pragma unroll
        for (int d = 1; d < 64; d <<= 1) ssm += __shfl_xor(ssm, d, 64);
        __syncthreads();
        if (lane == 0) swred[tid >> 6] = ssm;
        __syncthreads();
        float Ssum = 0.f;
        #pragma unroll
        for (int w = 0; w < 8; ++w) Ssum += swred[w];
        float logZ = M + logf(Ssum);
        if (tid < 128) out_slot[((size_t)bs * 1024 + t) * 128 + tid] = v - logZ;
        float av = v;
        int ai = (tid < 128) ? tid : (1 << 20);
        #pragma unroll
        for (int d = 1; d < 64; d <<= 1) {
          float ov = __shfl_xor(av, d, 64);
          int oi = __shfl_xor(ai, d, 64);
          if (ov > av || (ov == av && oi < ai)) { av = ov; ai = oi; }
        }
        if (lane == 0) { swav[tid >> 6] = av; swai[tid >> 6] = ai; }
        __syncthreads();
        if (tid == 0) {
          float bv = swav[0]; int bidx = swai[0];
          #pragma unroll
          for (int w = 1; w < 8; ++w)
            if (swav[w] > bv || (swav[w] == bv && swai[w] < bidx)) { bv = swav[w]; bidx = swai[w]; }
          sel[bs] = (unsigned)bidx;  // argmax ties: first index, matches jnp.argmax
        }
      }
    }
    __syncthreads();
    // reload updated h rows into LDS for next step (skip finished b's)
    {
      const float4* h4 = (const float4*)(hbuf + (size_t)b0 * 512);
      float4* hs4 = (float4*)(&hs[0][0]);
      for (int i = tid; i < 1024; i += 512)
        if (t < lenS[i >> 7]) hs4[i] = h4[i];
    }
    group_barrier(myctr, 32u * (2u * (unsigned)t + 2u));
  }

  if (g == 0) cbuf[(size_t)b * 512 + pglob] = cr;  // persist c across chunk launches
}

// ---------------------------------------------------------------- launch
extern "C" void kernel_launch(void* const* d_in, const int* in_sizes, int n_in,
                              void* d_out, int out_size, void* d_ws, size_t ws_size,
                              hipStream_t stream) {
  (void)in_sizes; (void)n_in; (void)out_size;
  const float* lstm_h = (const float*)d_in[0];
  const float* lstm_c = (const float*)d_in[1];
  const float* enc = (const float*)d_in[2];
  const int* lens = (const int*)d_in[3];
  const float* att_w = (const float*)d_in[4];
  const float* att_b = (const float*)d_in[5];
  const float* W_ih = (const float*)d_in[6];
  const float* b_ih = (const float*)d_in[7];
  const float* W_hh = (const float*)d_in[8];
  const float* b_hh = (const float*)d_in[9];
  const float* W_slot = (const float*)d_in[10];
  const float* b_slot = (const float*)d_in[11];
  const float* table = (const float*)d_in[12];
  const float* init_s = (const float*)d_in[13];
  const float* W_int = (const float*)d_in[14];
  const float* b_int = (const float*)d_in[15];
  float* out = (float*)d_out;
  float* ws = (float*)d_ws;

  hipLaunchKernelGGL(k_init, dim3(4096), dim3(256), 0, stream, out, lstm_h, lstm_c, ws);
  hipLaunchKernelGGL(k_att_logits, dim3(16384), dim3(256), 0, stream, enc, att_w, att_b, ws + OFF_LOGITS);
  hipLaunchKernelGGL(k_att_ctx, dim3(64), dim3(256), 0, stream, enc, ws + OFF_LOGITS, lens, ws + OFF_CTX, ws + OFF_POOL);
  hipLaunchKernelGGL(k_intent, dim3(64), dim3(128), 0, stream, ws + OFF_CTX, ws + OFF_POOL, W_int, b_int, out + 8388608);
  hipLaunchKernelGGL(k_wh, dim3(1024), dim3(256), 0, stream, W_ih, W_hh, ws + OFF_WH);
  hipLaunchKernelGGL(k_embw, dim3(1032), dim3(256), 0, stream, W_ih, table, init_s, ws + OFF_EMBW);
  hipLaunchKernelGGL(k_prectx, dim3(512), dim3(256), 0, stream, W_ih, ws + OFF_CTX, b_ih, b_hh, ws + OFF_PRECTX);

  // adaptive chunking of pre_enc to fit ws
  size_t availF = ws_size / 4;
  size_t preF = (availF > (size_t)OFF_PRE) ? (availF - (size_t)OFF_PRE) : 0;
  int Tc = (int)(preF / (64 * 2048));
  if (Tc > 1024) Tc = 1024;
  if (Tc < 1) Tc = 1;
  for (int ct0 = 0; ct0 < 1024; ct0 += Tc) {
    int tc = (1024 - ct0 < Tc) ? (1024 - ct0) : Tc;
    hipLaunchKernelGGL(k_pre_enc, dim3(tc, 32), dim3(256), 0, stream, enc, W_ih, ws + OFF_PRE, ct0);
    hipLaunchKernelGGL(k_scan, dim3(256), dim3(512), 0, stream, ws, lens, W_slot, b_slot, out, ct0, ct0 + tc, ct0);
  }
}

// Round 3
// 44765.146 us; speedup vs baseline: 1.9445x; 1.9445x over previous
//
#include <hip/hip_runtime.h>
#include <cstdint>
#include <cstddef>

// Problem constants
#define BB 64
#define TT 1024
#define HH 512
#define EE 128
#define SS 128
#define II 32

// ws offsets (in floats)
#define OFF_LOGITS 0          // 65536
#define OFF_CTX    65536      // 32768
#define OFF_POOL   98304      // 32768
#define OFF_PRECTX 131072     // 131072  (B x 4H), includes b_ih+b_hh
#define OFF_WH     262144     // 1048576 (4H x H)
#define OFF_EMBW   1310720    // 129*2048 = 264192
#define OFF_HBUF   1574912    // 32768
#define OFF_CBUF   1607680    // 32768
#define OFF_SEL    1640448    // 64 uints
#define OFF_CTR    1640512    // 512 uints (8 groups x 64 padding)
#define OFF_PRE    2097152    // chunked pre_enc: Tc*64*2048 (includes prectx+biases)

// ---------------------------------------------------------------- init
__global__ void k_init(float* out, const float* lstm_h, const float* lstm_c, float* ws) {
  size_t gid = (size_t)blockIdx.x * 256 + threadIdx.x;
  float4* o4 = (float4*)out;
  const float4 z = make_float4(0.f, 0.f, 0.f, 0.f);
  for (size_t i = gid; i < 2097152u; i += (size_t)gridDim.x * 256) o4[i] = z; // zero slot_logp
  if (gid < 8192) {
    ((float4*)(ws + OFF_HBUF))[gid] = ((const float4*)lstm_h)[gid];
    ((float4*)(ws + OFF_CBUF))[gid] = ((const float4*)lstm_c)[gid];
  }
  if (gid < 64)  ((unsigned*)(ws + OFF_SEL))[gid] = 128u;  // init_slot row
  if (gid < 512) ((unsigned*)(ws + OFF_CTR))[gid] = 0u;
}

// ------------------------------------------------------- attention logits
__global__ void k_att_logits(const float* __restrict__ enc, const float* __restrict__ att_w,
                             const float* __restrict__ att_b, float* __restrict__ logits) {
  int row = blockIdx.x * 4 + (threadIdx.x >> 6);  // row = b*1024 + t
  int lane = threadIdx.x & 63;
  const float* er = enc + (size_t)row * HH;
  const float* w2 = att_w + HH;
  float acc = 0.f;
  #pragma unroll
  for (int j = 0; j < 8; ++j) acc = fmaf(er[lane + j * 64], w2[lane + j * 64], acc);
  #pragma unroll
  for (int d = 1; d < 64; d <<= 1) acc += __shfl_xor(acc, d, 64);
  if (lane == 0) logits[row] = acc + att_b[0];
}

// --------------------------------------- softmax + context + pooled (per b)
__global__ void k_att_ctx(const float* __restrict__ enc, const float* __restrict__ logits,
                          const int* __restrict__ lens, float* __restrict__ ctx,
                          float* __restrict__ pool) {
  int b = blockIdx.x, tid = threadIdx.x;
  int len = lens[b];
  __shared__ float ew[TT];
  __shared__ float red[8];
  float m = -3.0e38f;
  for (int t = tid; t < TT; t += 256) m = fmaxf(m, (t < len) ? logits[b * TT + t] : -3.0e38f);
  #pragma unroll
  for (int d = 1; d < 64; d <<= 1) m = fmaxf(m, __shfl_xor(m, d, 64));
  if ((tid & 63) == 0) red[tid >> 6] = m;
  __syncthreads();
  m = fmaxf(fmaxf(red[0], red[1]), fmaxf(red[2], red[3]));
  __syncthreads();
  float s = 0.f;
  for (int t = tid; t < TT; t += 256) {
    float e = (t < len) ? expf(logits[b * TT + t] - m) : 0.f;
    ew[t] = e; s += e;
  }
  #pragma unroll
  for (int d = 1; d < 64; d <<= 1) s += __shfl_xor(s, d, 64);
  if ((tid & 63) == 0) red[tid >> 6] = s;
  __syncthreads();
  s = red[0] + red[1] + red[2] + red[3];
  float inv = 1.f / s;
  float invlen = 1.f / (float)len;
  float c0 = 0.f, c1 = 0.f, p0 = 0.f, p1 = 0.f;
  const float* eb = enc + (size_t)b * TT * HH;
  for (int t = 0; t < TT; ++t) {
    float e = ew[t];
    float x0 = eb[t * HH + tid];
    float x1 = eb[t * HH + tid + 256];
    c0 = fmaf(e, x0, c0); c1 = fmaf(e, x1, c1);
    if (t < len) { p0 += x0; p1 += x1; }
  }
  ctx[b * HH + tid] = c0 * inv;
  ctx[b * HH + tid + 256] = c1 * inv;
  pool[b * HH + tid] = p0 * invlen;
  pool[b * HH + tid + 256] = p1 * invlen;
}

// ----------------------------------------------------------------- intent
__global__ void k_intent(const float* __restrict__ ctx, const float* __restrict__ pool,
                         const float* __restrict__ W_int, const float* __restrict__ b_int,
                         float* __restrict__ out_int) {
  int b = blockIdx.x, tid = threadIdx.x;  // 128 threads
  __shared__ float x[1024];
  __shared__ float lg[II];
  __shared__ float lz;
  for (int i = tid; i < HH; i += 128) { x[i] = ctx[b * HH + i]; x[HH + i] = pool[b * HH + i]; }
  __syncthreads();
  int s = tid >> 2, q = tid & 3;
  const float* wr = W_int + (size_t)s * 1024 + q * 256;
  const float* xr = x + q * 256;
  float acc = 0.f;
  #pragma unroll 4
  for (int k = 0; k < 256; ++k) acc = fmaf(wr[k], xr[k], acc);
  acc += __shfl_xor(acc, 1, 64);
  acc += __shfl_xor(acc, 2, 64);
  if (q == 0) lg[s] = acc + b_int[s];
  __syncthreads();
  if (tid == 0) {
    float M = lg[0];
    for (int i = 1; i < II; ++i) M = fmaxf(M, lg[i]);
    float S = 0.f;
    for (int i = 0; i < II; ++i) S += expf(lg[i] - M);
    lz = M + logf(S);
  }
  __syncthreads();
  if (tid < II) out_int[b * II + tid] = lg[tid] - lz;
}

// ------------------------------------------------- Wh = W_ih[:, :H] + W_hh
__global__ void k_wh(const float* __restrict__ W_ih, const float* __restrict__ W_hh,
                     float* __restrict__ Wh) {
  int i = blockIdx.x * 256 + threadIdx.x;  // float4 index, 262144 total
  int r = i >> 7, kq = i & 127;
  float4 a = ((const float4*)W_ih)[(size_t)r * 416 + kq];  // 1664/4 = 416
  float4 c = ((const float4*)W_hh)[i];
  ((float4*)Wh)[i] = make_float4(a.x + c.x, a.y + c.y, a.z + c.z, a.w + c.w);
}

// -------------------------------- embW[s][r] = emb_s . W_ih[r, 512:640]
__global__ void k_embw(const float* __restrict__ W_ih, const float* __restrict__ table,
                       const float* __restrict__ init_slot, float* __restrict__ embW) {
  int idx = blockIdx.x * 256 + threadIdx.x;  // 129*2048 = 264192 exact
  int s = idx >> 11, rr = idx & 2047;
  const float* tr = (s < SS) ? (table + (size_t)s * EE) : init_slot;
  const float* wr = W_ih + (size_t)rr * 1664 + 512;
  float a0 = 0.f, a1 = 0.f, a2 = 0.f, a3 = 0.f;
  #pragma unroll 4
  for (int e = 0; e < EE; e += 4) {
    a0 = fmaf(tr[e + 0], wr[e + 0], a0);
    a1 = fmaf(tr[e + 1], wr[e + 1], a1);
    a2 = fmaf(tr[e + 2], wr[e + 2], a2);
    a3 = fmaf(tr[e + 3], wr[e + 3], a3);
  }
  embW[idx] = (a0 + a1) + (a2 + a3);
}

// ------ prectx[b][r] = ctx[b] . W_ih[r,1152:1664] + b_ih[r] + b_hh[r]
__global__ void k_prectx(const float* __restrict__ W_ih, const float* __restrict__ ctx,
                         const float* __restrict__ b_ih, const float* __restrict__ b_hh,
                         float* __restrict__ pre) {
  int idx = blockIdx.x * 256 + threadIdx.x;  // 131072
  int b = idx >> 11, rr = idx & 2047;
  const float* cr = ctx + (size_t)b * HH;
  const float* wr = W_ih + (size_t)rr * 1664 + 1152;
  float a0 = 0.f, a1 = 0.f, a2 = 0.f, a3 = 0.f;
  #pragma unroll 4
  for (int k = 0; k < HH; k += 4) {
    a0 = fmaf(cr[k + 0], wr[k + 0], a0);
    a1 = fmaf(cr[k + 1], wr[k + 1], a1);
    a2 = fmaf(cr[k + 2], wr[k + 2], a2);
    a3 = fmaf(cr[k + 3], wr[k + 3], a3);
  }
  pre[idx] = (a0 + a1) + (a2 + a3) + b_ih[rr] + b_hh[rr];
}

// -- pre_enc chunk GEMM: pre[(tl*64+b)][r] = enc[b,t,:].W_enc[r,:] + prectx[b][r]
__global__ __launch_bounds__(256, 2) void k_pre_enc(const float* __restrict__ enc,
                                                    const float* __restrict__ W_ih,
                                                    const float* __restrict__ prectx,
                                                    float* __restrict__ pre, int ct0) {
  const int tl = blockIdx.x;
  const int r0 = blockIdx.y * 64;
  const int tg = ct0 + tl;
  const int tid = threadIdx.x;
  __shared__ float As[16][68];
  __shared__ float Bs[16][68];
  float acc[4][4] = {{0.f}};
  const int i4 = tid >> 4, j4 = tid & 15;
  const int lr = tid >> 2;
  const int lk = (tid & 3) * 4;
  const float* encb = enc + (size_t)lr * (TT * HH) + (size_t)tg * HH;  // row b = lr
  const float* wb = W_ih + (size_t)(r0 + lr) * 1664 + 640;
  for (int ks = 0; ks < HH; ks += 16) {
    float4 av = *(const float4*)(encb + ks + lk);
    float4 bv = *(const float4*)(wb + ks + lk);
    __syncthreads();
    As[lk + 0][lr] = av.x; As[lk + 1][lr] = av.y; As[lk + 2][lr] = av.z; As[lk + 3][lr] = av.w;
    Bs[lk + 0][lr] = bv.x; Bs[lk + 1][lr] = bv.y; Bs[lk + 2][lr] = bv.z; Bs[lk + 3][lr] = bv.w;
    __syncthreads();
    #pragma unroll
    for (int kk = 0; kk < 16; ++kk) {
      float4 a4 = *(const float4*)(&As[kk][i4 * 4]);
      float4 b4 = *(const float4*)(&Bs[kk][j4 * 4]);
      acc[0][0] = fmaf(a4.x, b4.x, acc[0][0]); acc[0][1] = fmaf(a4.x, b4.y, acc[0][1]);
      acc[0][2] = fmaf(a4.x, b4.z, acc[0][2]); acc[0][3] = fmaf(a4.x, b4.w, acc[0][3]);
      acc[1][0] = fmaf(a4.y, b4.x, acc[1][0]); acc[1][1] = fmaf(a4.y, b4.y, acc[1][1]);
      acc[1][2] = fmaf(a4.y, b4.z, acc[1][2]); acc[1][3] = fmaf(a4.y, b4.w, acc[1][3]);
      acc[2][0] = fmaf(a4.z, b4.x, acc[2][0]); acc[2][1] = fmaf(a4.z, b4.y, acc[2][1]);
      acc[2][2] = fmaf(a4.z, b4.z, acc[2][2]); acc[2][3] = fmaf(a4.z, b4.w, acc[2][3]);
      acc[3][0] = fmaf(a4.w, b4.x, acc[3][0]); acc[3][1] = fmaf(a4.w, b4.y, acc[3][1]);
      acc[3][2] = fmaf(a4.w, b4.z, acc[3][2]); acc[3][3] = fmaf(a4.w, b4.w, acc[3][3]);
    }
  }
  #pragma unroll
  for (int ii = 0; ii < 4; ++ii) {
    int brow = i4 * 4 + ii;
    float4 pc = *(const float4*)(prectx + (size_t)brow * 2048 + r0 + j4 * 4);
    float* po = pre + ((size_t)tl * 64 + brow) * 2048 + r0 + j4 * 4;
    *((float4*)po) = make_float4(acc[ii][0] + pc.x, acc[ii][1] + pc.y,
                                 acc[ii][2] + pc.z, acc[ii][3] + pc.w);
  }
}

// ---------------------------------------------------------------- scan
// 8 groups of 32 blocks; group g = blocks with blockIdx&7==g (same XCD under
// round-robin dispatch). Wh register-resident: 64 rows/block = 64 fl/thread.
__device__ __forceinline__ void group_barrier(unsigned* c, unsigned target) {
  __syncthreads();
  if (threadIdx.x == 0) {
    unsigned old = __hip_atomic_fetch_add(c, 1u, __ATOMIC_ACQ_REL, __HIP_MEMORY_SCOPE_AGENT);
    if (old + 1u < target) {
      int polls = 0;
      while (__hip_atomic_load(c, __ATOMIC_ACQUIRE, __HIP_MEMORY_SCOPE_AGENT) < target) {
        if (++polls > 32) __builtin_amdgcn_s_sleep(1);
      }
    }
  }
  __syncthreads();
}

__global__ __launch_bounds__(512, 2) void k_scan(float* ws, const int* __restrict__ seq_lens,
                                                 const float* __restrict__ W_slot_g,
                                                 const float* __restrict__ b_slot,
                                                 float* __restrict__ out_slot,
                                                 int t0, int t1, int ct0) {
  float* hbuf = ws + OFF_HBUF;
  float* cbuf = ws + OFF_CBUF;
  unsigned* sel = (unsigned*)(ws + OFF_SEL);
  unsigned* ctr = (unsigned*)(ws + OFF_CTR);
  const float* WhG = ws + OFF_WH;
  const float* embW = ws + OFF_EMBW;
  const float* pre = ws + OFF_PRE;

  const int gid = blockIdx.x;
  const int grp = gid & 7;        // 8 groups (XCD-aligned under round-robin)
  const int bk = gid >> 3;        // 32 blocks per group
  const int b0 = grp * 8;
  const int tid = threadIdx.x;
  const int lane = tid & 63;
  const int rg = tid >> 4;        // 0..31 : row-pair group
  const int ks = tid & 15;        // 0..15 : k-slice of 32 floats
  unsigned* myctr = ctr + grp * 64;

  // global gate-row for local row r_l (0..63): r = g*512 + bk*16 + p
  const int rl0 = rg * 2, rl1 = rg * 2 + 1;
  const int r0g = (rl0 >> 4) * 512 + bk * 16 + (rl0 & 15);
  const int r1g = (rl1 >> 4) * 512 + bk * 16 + (rl1 & 15);
  // output owned by this lane after reduce-scatter: index ks -> (rr=ks>>3, b=ks&7)
  const int orr = ks >> 3, ob = ks & 7;
  const int r_out = ((rg * 2 + orr) >> 4) * 512 + bk * 16 + ((rg * 2 + orr) & 15);
  const int b_out = b0 + ob;

  // ---- register-resident weights
  float4 w0r[8], w1r[8];
  #pragma unroll
  for (int j = 0; j < 8; ++j) {
    w0r[j] = *(const float4*)(WhG + (size_t)r0g * 512 + ks * 32 + j * 4);
    w1r[j] = *(const float4*)(WhG + (size_t)r1g * 512 + ks * 32 + j * 4);
  }
  float4 wslot[32];
  if (bk < 8) {
    const float* wsrc = W_slot_g + (size_t)(tid >> 2) * 512 + (tid & 3) * 128;
    #pragma unroll
    for (int j = 0; j < 32; ++j) wslot[j] = *(const float4*)(wsrc + j * 4);
  }

  __shared__ float h8p[8 * 544];  // b*544 + (k>>5)*34 + (k&31): 16 banks, b-free
  __shared__ float garr[64 * 9];  // r_l*9 + b
  __shared__ float carr[128];     // p*8 + b
  __shared__ float slog[128];
  __shared__ float swred[8];
  __shared__ float swav[8];
  __shared__ int swai[8];
  __shared__ int lenS[8];

  if (tid < 8) lenS[tid] = seq_lens[b0 + tid];
  if (tid < 128) carr[tid] = cbuf[(size_t)(b0 + (tid & 7)) * 512 + bk * 16 + (tid >> 3)];
  __syncthreads();
  int gmax = 0;
  #pragma unroll
  for (int i = 0; i < 8; ++i) gmax = max(gmax, lenS[i]);
  const int tmax = min(t1, gmax);

  // stage h8p <- hbuf (wave = local b, lane covers 8 floats)
  const int stb = tid >> 6;
  const int stk = lane * 8;
  {
    const float4* src = (const float4*)(hbuf + (size_t)(b0 + stb) * 512 + stk);
    float4 v0 = src[0], v1 = src[1];
    float* dst = h8p + stb * 544 + (stk >> 5) * 34 + (stk & 31);
    *(float4*)dst = v0; *(float4*)(dst + 4) = v1;
  }
  __syncthreads();

  for (int t = t0; t < tmax; ++t) {
    // prefetch per-(r_out,b_out) addends (sel is from step t-1, visible)
    float pre_v = pre[((size_t)(t - ct0) * 64 + b_out) * 2048 + r_out];
    float emb_v = embW[(size_t)sel[b_out] * 2048 + r_out];

    // ---- gate GEMV: 2 rows x 8 b x 32 k per thread, h from LDS
    float a[16];
    #pragma unroll
    for (int i = 0; i < 16; ++i) a[i] = 0.f;
    const float* hb = h8p + ks * 34;
    #pragma unroll
    for (int j = 0; j < 8; ++j) {
      float4 wa = w0r[j], wb = w1r[j];
      #pragma unroll
      for (int b = 0; b < 8; ++b) {
        float4 hv = *(const float4*)(hb + b * 544 + j * 4);
        a[b]     = fmaf(wa.x, hv.x, a[b]);
        a[b]     = fmaf(wa.y, hv.y, a[b]);
        a[b]     = fmaf(wa.z, hv.z, a[b]);
        a[b]     = fmaf(wa.w, hv.w, a[b]);
        a[8 + b] = fmaf(wb.x, hv.x, a[8 + b]);
        a[8 + b] = fmaf(wb.y, hv.y, a[8 + b]);
        a[8 + b] = fmaf(wb.z, hv.z, a[8 + b]);
        a[8 + b] = fmaf(wb.w, hv.w, a[8 + b]);
      }
    }
    // ---- reduce-scatter over the 16 ks-lanes: lane ks ends with sum of a[ks]
    float t8[8], t4[4], t2[2], val;
    {
      bool h1 = (ks & 1);
      #pragma unroll
      for (int m = 0; m < 8; ++m) {
        float keep = h1 ? a[2 * m + 1] : a[2 * m];
        float send = h1 ? a[2 * m] : a[2 * m + 1];
        t8[m] = keep + __shfl_xor(send, 1, 64);
      }
      bool h2 = (ks & 2);
      #pragma unroll
      for (int m = 0; m < 4; ++m) {
        float keep = h2 ? t8[2 * m + 1] : t8[2 * m];
        float send = h2 ? t8[2 * m] : t8[2 * m + 1];
        t4[m] = keep + __shfl_xor(send, 2, 64);
      }
      bool h3 = (ks & 4);
      #pragma unroll
      for (int m = 0; m < 2; ++m) {
        float keep = h3 ? t4[2 * m + 1] : t4[2 * m];
        float send = h3 ? t4[2 * m] : t4[2 * m + 1];
        t2[m] = keep + __shfl_xor(send, 4, 64);
      }
      bool h4 = (ks & 8);
      float keep = h4 ? t2[1] : t2[0];
      float send = h4 ? t2[0] : t2[1];
      val = keep + __shfl_xor(send, 8, 64);
    }
    val += pre_v + emb_v;
    garr[(rg * 2 + orr) * 9 + ob] = val;
    __syncthreads();

    // ---- pointwise LSTM update for this block's 16 h-dims x 8 b
    if (tid < 128) {
      int p = tid >> 3, b = tid & 7;
      if (t < lenS[b]) {
        float gi = garr[(p) * 9 + b];
        float gf = garr[(16 + p) * 9 + b];
        float gg = garr[(32 + p) * 9 + b];
        float go = garr[(48 + p) * 9 + b];
        float si = 1.f / (1.f + expf(-gi));
        float sf = 1.f / (1.f + expf(-gf));
        float so = 1.f / (1.f + expf(-go));
        float cold = carr[p * 8 + b];
        float c_new = fmaf(sf, cold, si * tanhf(gg));
        float h_new = so * tanhf(c_new);
        carr[p * 8 + b] = c_new;
        hbuf[(size_t)(b0 + b) * 512 + bk * 16 + p] = h_new;
      }
    }
    group_barrier(myctr, 32u * (2u * (unsigned)t + 1u));  // h(t) visible

    // ---- all blocks: restage h8p <- h(t)
    {
      const float4* src = (const float4*)(hbuf + (size_t)(b0 + stb) * 512 + stk);
      float4 v0 = src[0], v1 = src[1];
      float* dst = h8p + stb * 544 + (stk >> 5) * 34 + (stk & 31);
      *(float4*)dst = v0; *(float4*)(dst + 4) = v1;
    }

    // ---- slot phase: blocks 0..7 of the group each own one b (reads h8p)
    if (bk < 8) {
      __syncthreads();  // h8p staged
      if (t < lenS[bk]) {
        const int s = tid >> 2, q = tid & 3;
        const float* hq = h8p + bk * 544 + (q * 4) * 34;
        float s0 = 0.f, s1 = 0.f, s2 = 0.f, s3 = 0.f;
        #pragma unroll
        for (int j = 0; j < 32; j += 4) {
          float4 h0 = *(const float4*)(hq + ((j + 0) >> 3) * 34 + ((j + 0) & 7) * 4);
          float4 h1 = *(const float4*)(hq + ((j + 1) >> 3) * 34 + ((j + 1) & 7) * 4);
          float4 h2 = *(const float4*)(hq + ((j + 2) >> 3) * 34 + ((j + 2) & 7) * 4);
          float4 h3 = *(const float4*)(hq + ((j + 3) >> 3) * 34 + ((j + 3) & 7) * 4);
          float4 w0 = wslot[j], w1 = wslot[j + 1], w2 = wslot[j + 2], w3 = wslot[j + 3];
          s0 = fmaf(w0.x, h0.x, s0); s0 = fmaf(w0.y, h0.y, s0);
          s0 = fmaf(w0.z, h0.z, s0); s0 = fmaf(w0.w, h0.w, s0);
          s1 = fmaf(w1.x, h1.x, s1); s1 = fmaf(w1.y, h1.y, s1);
          s1 = fmaf(w1.z, h1.z, s1); s1 = fmaf(w1.w, h1.w, s1);
          s2 = fmaf(w2.x, h2.x, s2); s2 = fmaf(w2.y, h2.y, s2);
          s2 = fmaf(w2.z, h2.z, s2); s2 = fmaf(w2.w, h2.w, s2);
          s3 = fmaf(w3.x, h3.x, s3); s3 = fmaf(w3.y, h3.y, s3);
          s3 = fmaf(w3.z, h3.z, s3); s3 = fmaf(w3.w, h3.w, s3);
        }
        float sacc = (s0 + s1) + (s2 + s3);
        sacc += __shfl_xor(sacc, 1, 64);
        sacc += __shfl_xor(sacc, 2, 64);
        sacc += b_slot[s];
        if (q == 0) slog[s] = sacc;
        __syncthreads();
        float v = (tid < 128) ? slog[tid] : -3.0e38f;
        float m = v;
        #pragma unroll
        for (int d = 1; d < 64; d <<= 1) m = fmaxf(m, __shfl_xor(m, d, 64));
        if (lane == 0) swred[tid >> 6] = m;
        __syncthreads();
        float M = swred[0];
        #pragma unroll
        for (int w = 1; w < 8; ++w) M = fmaxf(M, swred[w]);
        float e = (tid < 128) ? expf(v - M) : 0.f;
        float ssm = e;
        #pragma unroll
        for (int d = 1; d < 64; d <<= 1) ssm += __shfl_xor(ssm, d, 64);
        __syncthreads();
        if (lane == 0) swred[tid >> 6] = ssm;
        __syncthreads();
        float Ssum = 0.f;
        #pragma unroll
        for (int w = 0; w < 8; ++w) Ssum += swred[w];
        float logZ = M + logf(Ssum);
        if (tid < 128) out_slot[((size_t)(b0 + bk) * 1024 + t) * 128 + tid] = v - logZ;
        float av = v;
        int ai = (tid < 128) ? tid : (1 << 20);
        #pragma unroll
        for (int d = 1; d < 64; d <<= 1) {
          float ov = __shfl_xor(av, d, 64);
          int oi = __shfl_xor(ai, d, 64);
          if (ov > av || (ov == av && oi < ai)) { av = ov; ai = oi; }
        }
        if (lane == 0) { swav[tid >> 6] = av; swai[tid >> 6] = ai; }
        __syncthreads();
        if (tid == 0) {
          float bv = swav[0]; int bidx = swai[0];
          #pragma unroll
          for (int w = 1; w < 8; ++w)
            if (swav[w] > bv || (swav[w] == bv && swai[w] < bidx)) { bv = swav[w]; bidx = swai[w]; }
          sel[b0 + bk] = (unsigned)bidx;  // first-index ties, matches jnp.argmax
        }
      }
    }
    group_barrier(myctr, 32u * (2u * (unsigned)t + 2u));  // sel(t) visible
  }

  // persist c across chunk launches
  if (tid < 128) cbuf[(size_t)(b0 + (tid & 7)) * 512 + bk * 16 + (tid >> 3)] = carr[tid];
}

// ---------------------------------------------------------------- launch
extern "C" void kernel_launch(void* const* d_in, const int* in_sizes, int n_in,
                              void* d_out, int out_size, void* d_ws, size_t ws_size,
                              hipStream_t stream) {
  (void)in_sizes; (void)n_in; (void)out_size;
  const float* lstm_h = (const float*)d_in[0];
  const float* lstm_c = (const float*)d_in[1];
  const float* enc = (const float*)d_in[2];
  const int* lens = (const int*)d_in[3];
  const float* att_w = (const float*)d_in[4];
  const float* att_b = (const float*)d_in[5];
  const float* W_ih = (const float*)d_in[6];
  const float* b_ih = (const float*)d_in[7];
  const float* W_hh = (const float*)d_in[8];
  const float* b_hh = (const float*)d_in[9];
  const float* W_slot = (const float*)d_in[10];
  const float* b_slot = (const float*)d_in[11];
  const float* table = (const float*)d_in[12];
  const float* init_s = (const float*)d_in[13];
  const float* W_int = (const float*)d_in[14];
  const float* b_int = (const float*)d_in[15];
  float* out = (float*)d_out;
  float* ws = (float*)d_ws;

  hipLaunchKernelGGL(k_init, dim3(4096), dim3(256), 0, stream, out, lstm_h, lstm_c, ws);
  hipLaunchKernelGGL(k_att_logits, dim3(16384), dim3(256), 0, stream, enc, att_w, att_b, ws + OFF_LOGITS);
  hipLaunchKernelGGL(k_att_ctx, dim3(64), dim3(256), 0, stream, enc, ws + OFF_LOGITS, lens, ws + OFF_CTX, ws + OFF_POOL);
  hipLaunchKernelGGL(k_intent, dim3(64), dim3(128), 0, stream, ws + OFF_CTX, ws + OFF_POOL, W_int, b_int, out + 8388608);
  hipLaunchKernelGGL(k_wh, dim3(1024), dim3(256), 0, stream, W_ih, W_hh, ws + OFF_WH);
  hipLaunchKernelGGL(k_embw, dim3(1032), dim3(256), 0, stream, W_ih, table, init_s, ws + OFF_EMBW);
  hipLaunchKernelGGL(k_prectx, dim3(512), dim3(256), 0, stream, W_ih, ws + OFF_CTX, b_ih, b_hh, ws + OFF_PRECTX);

  // adaptive chunking of pre_enc to fit ws
  size_t availF = ws_size / 4;
  size_t preF = (availF > (size_t)OFF_PRE) ? (availF - (size_t)OFF_PRE) : 0;
  int Tc = (int)(preF / (64 * 2048));
  if (Tc > 1024) Tc = 1024;
  if (Tc < 1) Tc = 1;
  for (int ct0 = 0; ct0 < 1024; ct0 += Tc) {
    int tc = (1024 - ct0 < Tc) ? (1024 - ct0) : Tc;
    hipLaunchKernelGGL(k_pre_enc, dim3(tc, 32), dim3(256), 0, stream, enc, W_ih, ws + OFF_PRECTX, ws + OFF_PRE, ct0);
    hipLaunchKernelGGL(k_scan, dim3(256), dim3(512), 0, stream, ws, lens, W_slot, b_slot, out, ct0, ct0 + tc, ct0);
  }
}